// Round 1
// baseline (2043.231 us; speedup 1.0000x reference)
//
#include <hip/hip_runtime.h>

typedef __attribute__((ext_vector_type(4))) float f32x4;
typedef __attribute__((ext_vector_type(8))) short bf16x8;

#define NB 4
#define NS 512
#define ND 512
#define NH 8
#define NMID 2048
#define DDW (ND*ND)      // 262144, one DxD weight matrix
#define SLAB 32768       // per (b,h) attention slab: 512x64
#define BSD (NS*ND)      // 262144, one batch of activations

// ---------- helpers ----------
__device__ __forceinline__ unsigned short f2bf_rne(float f) {
    unsigned u = __float_as_uint(f);
    unsigned r = u + 0x7FFFu + ((u >> 16) & 1u);
    return (unsigned short)(r >> 16);
}

__device__ __forceinline__ float wave_sum(float v) {
#pragma unroll
    for (int off = 32; off; off >>= 1) v += __shfl_xor(v, off, 64);
    return v;
}
__device__ __forceinline__ float wave_max(float v) {
#pragma unroll
    for (int off = 32; off; off >>= 1) v = fmaxf(v, __shfl_xor(v, off, 64));
    return v;
}

// ---------- embedding + positional (quirk: pos indexed by batch) ----------
__global__ __launch_bounds__(256) void embed_k(const int* __restrict__ toks,
                                               const float* __restrict__ emb,
                                               const float* __restrict__ pos,
                                               float* __restrict__ x) {
    int idx = blockIdx.x * 256 + threadIdx.x;     // float4 index, total 262144
    int d4 = idx & 127;                           // D/4 = 128
    int s  = (idx >> 7) & 511;
    int b  = idx >> 16;                           // 128*512 f4 per batch
    int tok = toks[b * NS + s];
    f32x4 e = *(const f32x4*)(emb + (long)tok * ND + d4 * 4);
    f32x4 p = *(const f32x4*)(pos + (long)b * ND + d4 * 4);
    *(f32x4*)(x + (long)idx * 4) = e + p;
}

// ---------- add + layernorm (one wave per row of 512) ----------
__global__ __launch_bounds__(256) void add_ln_k(const float* __restrict__ a,
                                                const float* __restrict__ b,
                                                const float* __restrict__ g,
                                                const float* __restrict__ bb,
                                                float* __restrict__ o) {
    int r = blockIdx.x * 4 + (threadIdx.x >> 6);
    int lane = threadIdx.x & 63;
    const float* pa = a + (long)r * ND + lane * 8;
    const float* pb = b + (long)r * ND + lane * 8;
    f32x4 va0 = *(const f32x4*)pa, va1 = *(const f32x4*)(pa + 4);
    f32x4 vb0 = *(const f32x4*)pb, vb1 = *(const f32x4*)(pb + 4);
    float v[8];
#pragma unroll
    for (int j = 0; j < 4; ++j) { v[j] = va0[j] + vb0[j]; v[4 + j] = va1[j] + vb1[j]; }
    float s = 0.f;
#pragma unroll
    for (int j = 0; j < 8; ++j) s += v[j];
    float mu = wave_sum(s) * (1.0f / 512.0f);
    float vs = 0.f;
#pragma unroll
    for (int j = 0; j < 8; ++j) { float d = v[j] - mu; vs += d * d; }
    float rs = rsqrtf(wave_sum(vs) * (1.0f / 512.0f) + 1e-5f);
    const float* gp = g + lane * 8; const float* bp = bb + lane * 8;
    f32x4 g0 = *(const f32x4*)gp, g1 = *(const f32x4*)(gp + 4);
    f32x4 b0 = *(const f32x4*)bp, b1 = *(const f32x4*)(bp + 4);
    f32x4 o0, o1;
#pragma unroll
    for (int j = 0; j < 4; ++j) {
        o0[j] = (v[j] - mu) * rs * g0[j] + b0[j];
        o1[j] = (v[4 + j] - mu) * rs * g1[j] + b1[j];
    }
    float* po = o + (long)r * ND + lane * 8;
    *(f32x4*)po = o0; *(f32x4*)(po + 4) = o1;
}

// ---------- softmax over rows of 512 (one wave per row), optional mask ----------
// MODE 0: no mask.  MODE 1: mask[b*512+k] (src_mask B,1,1,S).  MODE 2: mask[b*512*512+q*512+k].
template <int MODE>
__global__ __launch_bounds__(256) void softmax_rows(float* __restrict__ sc,
                                                    const int* __restrict__ mask) {
    int r = blockIdx.x * 4 + (threadIdx.x >> 6);  // global row over B*H*512 = 16384
    int lane = threadIdx.x & 63;
    float* row = sc + (long)r * 512;
    int b = r >> 12;        // 4096 rows per batch
    int q = r & 511;
    f32x4 v0 = *(f32x4*)(row + lane * 8);
    f32x4 v1 = *(f32x4*)(row + lane * 8 + 4);
    float v[8];
#pragma unroll
    for (int j = 0; j < 4; ++j) { v[j] = v0[j]; v[4 + j] = v1[j]; }
    if (MODE == 1) {
        const int* mp = mask + (long)b * 512 + lane * 8;
#pragma unroll
        for (int j = 0; j < 8; ++j) if (mp[j] == 0) v[j] = -3.4e38f;
    }
    if (MODE == 2) {
        const int* mp = mask + (long)b * 512 * 512 + (long)q * 512 + lane * 8;
#pragma unroll
        for (int j = 0; j < 8; ++j) if (mp[j] == 0) v[j] = -3.4e38f;
    }
    float mx = -3.4e38f;
#pragma unroll
    for (int j = 0; j < 8; ++j) mx = fmaxf(mx, v[j]);
    mx = wave_max(mx);
    float s = 0.f;
#pragma unroll
    for (int j = 0; j < 8; ++j) { v[j] = __expf(v[j] - mx); s += v[j]; }
    float inv = 1.0f / wave_sum(s);
#pragma unroll
    for (int j = 0; j < 4; ++j) { v0[j] = v[j] * inv; v1[j] = v[4 + j] * inv; }
    *(f32x4*)(row + lane * 8) = v0;
    *(f32x4*)(row + lane * 8 + 4) = v1;
}

// ---------- V-slab transpose: vt[b][h][j][s2] = vb[b][h*32768 + s2*64 + j] ----------
__global__ __launch_bounds__(256) void transpose_v(const float* __restrict__ vb,
                                                   float* __restrict__ vt) {
    int z = blockIdx.x;    // b*H+h : 0..31
    int s2t = blockIdx.y;  // 0..7  (64 s2 per tile)
    __shared__ float tile[64][65];
    const float* src = vb + (long)z * SLAB + (long)s2t * 64 * 64;
    int tid = threadIdx.x;
#pragma unroll
    for (int it = 0; it < 16; ++it) {
        int idx = it * 256 + tid;
        int s2l = idx >> 6, j = idx & 63;
        tile[j][s2l] = src[idx];
    }
    __syncthreads();
    float* dst = vt + (long)z * SLAB + s2t * 64;
#pragma unroll
    for (int it = 0; it < 16; ++it) {
        int idx = it * 256 + tid;
        int jl = idx >> 6, s2l = idx & 63;
        dst[(long)jl * 512 + s2l] = tile[jl][s2l];
    }
}

// ---------- split-precision bf16 MFMA GEMM: C = alpha*(A @ W^T) + bias ----------
// A: (M,K) fp32 lda ; W: (N,K) fp32 ldw ; C fp32 ldc.
// acc = Ahi*Whi + Ahi*Wlo + Alo*Whi  (~fp32 accuracy).
// Batched over grid.z: A += z*aZ, W += z*wZ, C += (z/bh)*cZb + (z%bh)*cZh.
// colMod/colBuf: fused-output-column split (QKV: cols [0,512) -> buf0, etc.).
template <int ROWS>
__device__ __forceinline__ void stage_tile(const float* __restrict__ src, int ld,
                                           unsigned short* hi, unsigned short* lo,
                                           int tid) {
    constexpr int ITER = ROWS / 16;  // (ROWS*16 f4) / 256 threads
#pragma unroll
    for (int i = 0; i < ITER; ++i) {
        int idx = i * 256 + tid;
        int row = idx >> 4, c4 = idx & 15;
        f32x4 v = *(const f32x4*)(src + (long)row * ld + c4 * 4);
        unsigned long long hp = 0ull, lp = 0ull;
#pragma unroll
        for (int j = 0; j < 4; ++j) {
            unsigned u = __float_as_uint(v[j]);
            float hf = __uint_as_float(u & 0xFFFF0000u);     // truncated hi
            unsigned short hbits = (unsigned short)(u >> 16);
            unsigned short lbits = f2bf_rne(v[j] - hf);      // residual lo
            hp |= (unsigned long long)hbits << (16 * j);
            lp |= (unsigned long long)lbits << (16 * j);
        }
        int byteoff = row * 128 + ((c4 * 8) ^ ((row & 7) << 4));  // XOR swizzle (G4)
        *(unsigned long long*)((char*)hi + byteoff) = hp;
        *(unsigned long long*)((char*)lo + byteoff) = lp;
    }
}

__device__ __forceinline__ bf16x8 ld_frag(const unsigned short* base, int row, int kbyte) {
    int byteoff = row * 128 + (kbyte ^ ((row & 7) << 4));
    return *(const bf16x8*)((const char*)base + byteoff);
}

template <int BM, int BN, bool RELU>
__global__ __launch_bounds__(256, 2) void gemm_split(
    const float* __restrict__ A, const float* __restrict__ W,
    const float* __restrict__ bias, float* __restrict__ C,
    int K, int lda, int ldw, int ldc, float alpha,
    long aZ, long wZ, long cZb, long cZh, int batch_h,
    int colMod, long colBuf) {
    constexpr int FR = BM / 32, FC = BN / 32;  // frags per wave (2x2 wave grid)
    __shared__ unsigned short Ah[BM * 64], Al[BM * 64], Bh[BN * 64], Bl[BN * 64];
    int tid = threadIdx.x;
    int z = blockIdx.z;
    int zb = z / batch_h, zh = z - zb * batch_h;
    const float* Ap = A + (long)z * aZ + (long)blockIdx.x * BM * lda;
    int bn0 = blockIdx.y * BN;
    const float* Wp = W + (long)z * wZ + (long)bn0 * ldw;
    float* Cp = C + (long)zb * cZb + (long)zh * cZh + (long)blockIdx.x * BM * ldc;
    int colbase = bn0;
    if (colMod) { int which = bn0 / colMod; Cp += (long)which * colBuf; colbase = bn0 - which * colMod; }

    f32x4 acc[FR][FC];
#pragma unroll
    for (int i = 0; i < FR; ++i)
#pragma unroll
        for (int j = 0; j < FC; ++j) acc[i][j] = (f32x4){0.f, 0.f, 0.f, 0.f};

    int wv = tid >> 6, lane = tid & 63;
    int wr = (wv >> 1) * (BM / 2), wc = (wv & 1) * (BN / 2);
    int lrow = lane & 15, lkb = (lane >> 4) * 16;  // k byte offset of this lane's 8 elems

    for (int kt = 0; kt < K; kt += 64) {
        __syncthreads();
        stage_tile<BM>(Ap + kt, lda, Ah, Al, tid);
        stage_tile<BN>(Wp + kt, ldw, Bh, Bl, tid);
        __syncthreads();
#pragma unroll
        for (int kk = 0; kk < 2; ++kk) {
            int kb = kk * 64 + lkb;
            bf16x8 ah[FR], al[FR], bh[FC], bl[FC];
#pragma unroll
            for (int i = 0; i < FR; ++i) {
                int rr = wr + i * 16 + lrow;
                ah[i] = ld_frag(Ah, rr, kb);
                al[i] = ld_frag(Al, rr, kb);
            }
#pragma unroll
            for (int j = 0; j < FC; ++j) {
                int cc = wc + j * 16 + lrow;
                bh[j] = ld_frag(Bh, cc, kb);
                bl[j] = ld_frag(Bl, cc, kb);
            }
#pragma unroll
            for (int i = 0; i < FR; ++i)
#pragma unroll
                for (int j = 0; j < FC; ++j) {
                    acc[i][j] = __builtin_amdgcn_mfma_f32_16x16x32_bf16(ah[i], bh[j], acc[i][j], 0, 0, 0);
                    acc[i][j] = __builtin_amdgcn_mfma_f32_16x16x32_bf16(ah[i], bl[j], acc[i][j], 0, 0, 0);
                    acc[i][j] = __builtin_amdgcn_mfma_f32_16x16x32_bf16(al[i], bh[j], acc[i][j], 0, 0, 0);
                }
        }
    }
    // epilogue: C/D layout col=lane&15, row=(lane>>4)*4+r  [m89]
#pragma unroll
    for (int i = 0; i < FR; ++i) {
        int rowl = wr + i * 16 + (lane >> 4) * 4;
#pragma unroll
        for (int j = 0; j < FC; ++j) {
            int coll = wc + j * 16 + lrow;
            float bv = bias ? bias[bn0 + coll] : 0.0f;
#pragma unroll
            for (int r = 0; r < 4; ++r) {
                float v = acc[i][j][r] * alpha + bv;
                if (RELU) v = fmaxf(v, 0.0f);
                Cp[(long)(rowl + r) * ldc + colbase + coll] = v;
            }
        }
    }
}

template <int BM, int BN, bool RELU>
static inline void launch_gemm(hipStream_t st, const float* A, const float* W,
                               const float* bias, float* C, int M, int N, int K,
                               int lda, int ldw, int ldc, float alpha,
                               long aZ, long wZ, long cZb, long cZh, int bh,
                               int colMod, long colBuf, int nz) {
    dim3 grid(M / BM, N / BN, nz);
    gemm_split<BM, BN, RELU><<<grid, 256, 0, st>>>(A, W, bias, C, K, lda, ldw, ldc,
                                                   alpha, aZ, wZ, cZb, cZh, bh, colMod, colBuf);
}

// ---------- orchestration ----------
extern "C" void kernel_launch(void* const* d_in, const int* in_sizes, int n_in,
                              void* d_out, int out_size, void* d_ws, size_t ws_size,
                              hipStream_t stream) {
    const int*   src_words    = (const int*)d_in[0];
    const float* target_words = (const float*)d_in[1];
    const int*   src_mask     = (const int*)d_in[2];
    const int*   target_mask  = (const int*)d_in[3];
    const float* emb          = (const float*)d_in[4];
    const float* pos_emb      = (const float*)d_in[5];
    const float* enc_ln_g     = (const float*)d_in[6];
    const float* enc_ln_b     = (const float*)d_in[7];
    const float* enc_attn_w   = (const float*)d_in[8];
    const float* enc_attn_b   = (const float*)d_in[9];
    const float* enc_fc1_w    = (const float*)d_in[10];
    const float* enc_fc1_b    = (const float*)d_in[11];
    const float* enc_fc2_w    = (const float*)d_in[12];
    const float* enc_fc2_b    = (const float*)d_in[13];
    const float* dec_ln_g     = (const float*)d_in[14];
    const float* dec_ln_b     = (const float*)d_in[15];
    const float* dec_self_w   = (const float*)d_in[16];
    const float* dec_self_b   = (const float*)d_in[17];
    const float* dec_src_w    = (const float*)d_in[18];
    const float* dec_src_b    = (const float*)d_in[19];
    const float* dec_fc1_w    = (const float*)d_in[20];
    const float* dec_fc1_b    = (const float*)d_in[21];
    const float* dec_fc2_w    = (const float*)d_in[22];
    const float* dec_fc2_b    = (const float*)d_in[23];
    float* out = (float*)d_out;

    const long M1 = 1 << 20;  // 1,048,576 floats per activation buffer
    float* ws    = (float*)d_ws;
    float* x_enc = ws;           float* t1  = ws + 1 * M1;  float* t2 = ws + 2 * M1;
    float* t3    = ws + 3 * M1;  float* qb  = ws + 4 * M1;  float* kb = ws + 5 * M1;
    float* vb    = ws + 6 * M1;  float* vt  = ws + 7 * M1;  float* ctx = ws + 8 * M1;
    float* ybuf  = ws + 9 * M1;  float* big = ws + 10 * M1; // big: 8M floats (scores / ffn-hidden)
    if (ws_size < (size_t)(10 * M1 + 8 * M1) * sizeof(float)) return;

    embed_k<<<1024, 256, 0, stream>>>(src_words, emb, pos_emb, x_enc);

    // ===== encoder =====
    for (int i = 0; i < 4; ++i) {
        const float* Wl = enc_attn_w + (size_t)i * 4 * DDW;
        const float* bl = enc_attn_b + (size_t)i * 4 * ND;
        const float* g  = enc_ln_g + (size_t)i * ND;
        const float* be = enc_ln_b + (size_t)i * ND;
        // fused QKV: N=1536 -> qb/kb/vb (colMod split)
        launch_gemm<128, 128, false>(stream, x_enc, Wl, bl, qb, 2048, 1536, 512,
                                     512, 512, 512, 1.f, 0, 0, 0, 0, 1, 512, M1, 1);
        transpose_v<<<dim3(32, 8), 256, 0, stream>>>(vb, vt);
        // scores = Q K^T / 8, batched over 32 slabs
        launch_gemm<128, 128, false>(stream, qb, kb, nullptr, big, 512, 512, 64,
                                     64, 64, 512, 0.125f, SLAB, SLAB, BSD, 0, 1, 0, 0, 32);
        softmax_rows<1><<<4096, 256, 0, stream>>>(big, src_mask);
        // ctx = P V, written into (B,S,D) layout at column block h*64
        launch_gemm<64, 64, false>(stream, big, vt, nullptr, ctx, 512, 64, 512,
                                   512, 512, 512, 1.f, BSD, SLAB, BSD, 64, 8, 0, 0, 32);
        // output projection
        launch_gemm<64, 64, false>(stream, ctx, Wl + 3 * DDW, bl + 3 * ND, t1, 2048, 512, 512,
                                   512, 512, 512, 1.f, 0, 0, 0, 0, 1, 0, 0, 1);
        add_ln_k<<<512, 256, 0, stream>>>(t1, x_enc, g, be, t2);
        // FFN
        launch_gemm<128, 128, true>(stream, t2, enc_fc1_w + (size_t)i * NMID * ND,
                                    enc_fc1_b + (size_t)i * NMID, big, 2048, 2048, 512,
                                    512, 512, 2048, 1.f, 0, 0, 0, 0, 1, 0, 0, 1);
        launch_gemm<64, 64, false>(stream, big, enc_fc2_w + (size_t)i * ND * NMID,
                                   enc_fc2_b + (size_t)i * ND, t1, 2048, 512, 2048,
                                   2048, 2048, 512, 1.f, 0, 0, 0, 0, 1, 0, 0, 1);
        add_ln_k<<<512, 256, 0, stream>>>(t1, t2, g, be, x_enc);
    }

    // ===== decoder =====
    const float* ystate = target_words;
    for (int i = 0; i < 4; ++i) {
        const float* Ws = dec_self_w + (size_t)i * 4 * DDW;
        const float* bs = dec_self_b + (size_t)i * 4 * ND;
        const float* Wx = dec_src_w + (size_t)i * 4 * DDW;
        const float* bx = dec_src_b + (size_t)i * 4 * ND;
        const float* g  = dec_ln_g + (size_t)i * ND;
        const float* be = dec_ln_b + (size_t)i * ND;
        // --- self attention ---
        launch_gemm<128, 128, false>(stream, ystate, Ws, bs, qb, 2048, 1536, 512,
                                     512, 512, 512, 1.f, 0, 0, 0, 0, 1, 512, M1, 1);
        transpose_v<<<dim3(32, 8), 256, 0, stream>>>(vb, vt);
        launch_gemm<128, 128, false>(stream, qb, kb, nullptr, big, 512, 512, 64,
                                     64, 64, 512, 0.125f, SLAB, SLAB, BSD, 0, 1, 0, 0, 32);
        softmax_rows<2><<<4096, 256, 0, stream>>>(big, target_mask);
        launch_gemm<64, 64, false>(stream, big, vt, nullptr, ctx, 512, 64, 512,
                                   512, 512, 512, 1.f, BSD, SLAB, BSD, 64, 8, 0, 0, 32);
        launch_gemm<64, 64, false>(stream, ctx, Ws + 3 * DDW, bs + 3 * ND, t1, 2048, 512, 512,
                                   512, 512, 512, 1.f, 0, 0, 0, 0, 1, 0, 0, 1);
        add_ln_k<<<512, 256, 0, stream>>>(t1, ystate, g, be, t2);
        // --- cross attention (Q from t2; K,V from encoder output) ---
        launch_gemm<64, 64, false>(stream, t2, Wx, bx, qb, 2048, 512, 512,
                                   512, 512, 512, 1.f, 0, 0, 0, 0, 1, 0, 0, 1);
        launch_gemm<64, 64, false>(stream, x_enc, Wx + DDW, bx + ND, kb, 2048, 1024, 512,
                                   512, 512, 512, 1.f, 0, 0, 0, 0, 1, 512, M1, 1);
        transpose_v<<<dim3(32, 8), 256, 0, stream>>>(vb, vt);
        launch_gemm<128, 128, false>(stream, qb, kb, nullptr, big, 512, 512, 64,
                                     64, 64, 512, 0.125f, SLAB, SLAB, BSD, 0, 1, 0, 0, 32);
        softmax_rows<0><<<4096, 256, 0, stream>>>(big, nullptr);
        launch_gemm<64, 64, false>(stream, big, vt, nullptr, ctx, 512, 64, 512,
                                   512, 512, 512, 1.f, BSD, SLAB, BSD, 64, 8, 0, 0, 32);
        launch_gemm<64, 64, false>(stream, ctx, Wx + 3 * DDW, bx + 3 * ND, t1, 2048, 512, 512,
                                   512, 512, 512, 1.f, 0, 0, 0, 0, 1, 0, 0, 1);
        add_ln_k<<<512, 256, 0, stream>>>(t1, t2, g, be, t3);
        // --- FFN ---
        launch_gemm<128, 128, true>(stream, t3, dec_fc1_w + (size_t)i * NMID * ND,
                                    dec_fc1_b + (size_t)i * NMID, big, 2048, 2048, 512,
                                    512, 512, 2048, 1.f, 0, 0, 0, 0, 1, 0, 0, 1);
        launch_gemm<64, 64, false>(stream, big, dec_fc2_w + (size_t)i * ND * NMID,
                                   dec_fc2_b + (size_t)i * ND, t1, 2048, 512, 2048,
                                   2048, 2048, 512, 1.f, 0, 0, 0, 0, 1, 0, 0, 1);
        add_ln_k<<<512, 256, 0, stream>>>(t1, t3, g, be, (i == 3) ? out : ybuf);
        ystate = ybuf;
    }
}

// Round 9
// 1660.351 us; speedup vs baseline: 1.2306x; 1.2306x over previous
//
#include <hip/hip_runtime.h>

typedef __attribute__((ext_vector_type(4))) float f32x4;
typedef __attribute__((ext_vector_type(8))) short bf16x8;
typedef unsigned short u16;
typedef __attribute__((ext_vector_type(8))) unsigned short u16x8;

#define NB 4
#define NS 512
#define ND 512
#define NMID 2048
#define DDW (ND*ND)

#define OUT_F32 0
#define OUT_SPLIT 1
#define OUT_SRELU 2
#define OUT_QKV 3

typedef const __attribute__((address_space(1))) void GV;
typedef __attribute__((address_space(3))) void LV;

// async global->LDS, 16B per lane, LDS dest = uniform base + lane*16
__device__ __forceinline__ void gl_lds16(const void* g, void* l) {
    __builtin_amdgcn_global_load_lds((GV*)g, (LV*)l, 16, 0, 0);
}

__device__ __forceinline__ u16 f2bf_rne(float f) {
    unsigned u = __float_as_uint(f);
    unsigned r = u + 0x7FFFu + ((u >> 16) & 1u);
    return (u16)(r >> 16);
}
// hi = truncated bf16, lo = rne(residual): hi+lo ~ fp32 (rel err ~2^-17)
__device__ __forceinline__ void split2(float v, u16& h, u16& l) {
    unsigned u = __float_as_uint(v);
    h = (u16)(u >> 16);
    float hf = __uint_as_float(u & 0xFFFF0000u);
    l = f2bf_rne(v - hf);
}

__device__ __forceinline__ float wave_sum(float v) {
#pragma unroll
    for (int off = 32; off; off >>= 1) v += __shfl_xor(v, off, 64);
    return v;
}
__device__ __forceinline__ float wave_max(float v) {
#pragma unroll
    for (int off = 32; off; off >>= 1) v = fmaxf(v, __shfl_xor(v, off, 64));
    return v;
}

// ---------- fp32 -> (hi,lo) bf16 split conversion ----------
__global__ __launch_bounds__(256) void split_conv(const float* __restrict__ in,
                                                  u16* __restrict__ hi,
                                                  u16* __restrict__ lo, int n8) {
    int t = blockIdx.x * 256 + threadIdx.x;
    if (t >= n8) return;
    const f32x4* p = (const f32x4*)(in + (long)t * 8);
    f32x4 a = p[0], b = p[1];
    u16x8 H, L;
#pragma unroll
    for (int j = 0; j < 4; ++j) {
        u16 h, l;
        split2(a[j], h, l); H[j] = h; L[j] = l;
        split2(b[j], h, l); H[4 + j] = h; L[4 + j] = l;
    }
    *(u16x8*)(hi + (long)t * 8) = H;
    *(u16x8*)(lo + (long)t * 8) = L;
}

// ---------- embedding + positional (quirk: pos row indexed by BATCH) ----------
__global__ __launch_bounds__(256) void embed_k(const int* __restrict__ toks,
                                               const float* __restrict__ emb,
                                               const float* __restrict__ pos,
                                               float* __restrict__ x,
                                               u16* __restrict__ xh, u16* __restrict__ xl) {
    int t = blockIdx.x * 256 + threadIdx.x;   // 131072 threads, 8 elems each
    int d8 = t & 63;
    int s  = (t >> 6) & 511;
    int b  = t >> 15;
    int tok = toks[b * NS + s];
    const float* ep = emb + (long)tok * ND + d8 * 8;
    const float* pp = pos + (long)b * ND + d8 * 8;
    f32x4 e0 = *(const f32x4*)ep, e1 = *(const f32x4*)(ep + 4);
    f32x4 p0 = *(const f32x4*)pp, p1 = *(const f32x4*)(pp + 4);
    f32x4 v0 = e0 + p0, v1 = e1 + p1;
    float* xp = x + (long)t * 8;
    *(f32x4*)xp = v0; *(f32x4*)(xp + 4) = v1;
    u16x8 H, L;
#pragma unroll
    for (int j = 0; j < 4; ++j) {
        u16 h, l;
        split2(v0[j], h, l); H[j] = h; L[j] = l;
        split2(v1[j], h, l); H[4 + j] = h; L[4 + j] = l;
    }
    *(u16x8*)(xh + (long)t * 8) = H;
    *(u16x8*)(xl + (long)t * 8) = L;
}

// ---------- add + layernorm, writes f32 + split ----------
__global__ __launch_bounds__(256) void add_ln_k(const float* __restrict__ a,
                                                const float* __restrict__ b,
                                                const float* __restrict__ g,
                                                const float* __restrict__ bb,
                                                float* __restrict__ o,
                                                u16* __restrict__ oh, u16* __restrict__ ol) {
    int r = blockIdx.x * 4 + (threadIdx.x >> 6);
    int lane = threadIdx.x & 63;
    const float* pa = a + (long)r * ND + lane * 8;
    const float* pb = b + (long)r * ND + lane * 8;
    f32x4 va0 = *(const f32x4*)pa, va1 = *(const f32x4*)(pa + 4);
    f32x4 vb0 = *(const f32x4*)pb, vb1 = *(const f32x4*)(pb + 4);
    float v[8];
#pragma unroll
    for (int j = 0; j < 4; ++j) { v[j] = va0[j] + vb0[j]; v[4 + j] = va1[j] + vb1[j]; }
    float s = 0.f;
#pragma unroll
    for (int j = 0; j < 8; ++j) s += v[j];
    float mu = wave_sum(s) * (1.0f / 512.0f);
    float vs = 0.f;
#pragma unroll
    for (int j = 0; j < 8; ++j) { float d = v[j] - mu; vs += d * d; }
    float rs = rsqrtf(wave_sum(vs) * (1.0f / 512.0f) + 1e-5f);
    const float* gp = g + lane * 8; const float* bp = bb + lane * 8;
    f32x4 g0 = *(const f32x4*)gp, g1 = *(const f32x4*)(gp + 4);
    f32x4 b0 = *(const f32x4*)bp, b1 = *(const f32x4*)(bp + 4);
    f32x4 o0, o1;
    u16x8 H, L;
#pragma unroll
    for (int j = 0; j < 4; ++j) {
        float x0 = (v[j] - mu) * rs * g0[j] + b0[j];
        float x1 = (v[4 + j] - mu) * rs * g1[j] + b1[j];
        o0[j] = x0; o1[j] = x1;
        u16 h, l;
        split2(x0, h, l); H[j] = h; L[j] = l;
        split2(x1, h, l); H[4 + j] = h; L[4 + j] = l;
    }
    float* po = o + (long)r * ND + lane * 8;
    *(f32x4*)po = o0; *(f32x4*)(po + 4) = o1;
    *(u16x8*)(oh + (long)r * ND + lane * 8) = H;
    *(u16x8*)(ol + (long)r * ND + lane * 8) = L;
}

// ---------- softmax over 512-wide rows; reads f32, writes split IN PLACE ----------
// row layout after: hi bf16 at ushorts [0,512), lo at [512,1024) of the same 2KB row.
// MODE 0: none. 1: mask[b*512+k]. 2: mask[b*512*512+q*512+k]. (q,k = reshaped pseudo-positions,
// faithful to reference broadcast over scores' last two axes.)
template <int MODE>
__global__ __launch_bounds__(256) void softmax_rows(float* __restrict__ sc,
                                                    const int* __restrict__ mask,
                                                    int zoff) {
    int r = blockIdx.x * 4 + (threadIdx.x >> 6);
    int lane = threadIdx.x & 63;
    float* row = sc + (long)r * 512;
    int gslab = zoff + (r >> 9);
    int b = gslab >> 3;
    int q = r & 511;
    f32x4 v0 = *(f32x4*)(row + lane * 8);
    f32x4 v1 = *(f32x4*)(row + lane * 8 + 4);
    float v[8];
#pragma unroll
    for (int j = 0; j < 4; ++j) { v[j] = v0[j]; v[4 + j] = v1[j]; }
    if (MODE == 1) {
        const int* mp = mask + (long)b * 512 + lane * 8;
#pragma unroll
        for (int j = 0; j < 8; ++j) if (mp[j] == 0) v[j] = -3.4e38f;
    }
    if (MODE == 2) {
        const int* mp = mask + (long)b * 512 * 512 + (long)q * 512 + lane * 8;
#pragma unroll
        for (int j = 0; j < 8; ++j) if (mp[j] == 0) v[j] = -3.4e38f;
    }
    float mx = -3.4e38f;
#pragma unroll
    for (int j = 0; j < 8; ++j) mx = fmaxf(mx, v[j]);
    mx = wave_max(mx);
    float s = 0.f;
#pragma unroll
    for (int j = 0; j < 8; ++j) { v[j] = __expf(v[j] - mx); s += v[j]; }
    float inv = 1.0f / wave_sum(s);
    u16x8 H, L;
#pragma unroll
    for (int j = 0; j < 8; ++j) {
        u16 h, l; split2(v[j] * inv, h, l);
        H[j] = h; L[j] = l;
    }
    u16* ru = (u16*)row;
    *(u16x8*)(ru + lane * 8) = H;          // hi half of row
    *(u16x8*)(ru + 512 + lane * 8) = L;    // lo half of row
}

// ---------- staging: R x 64 bf16 tile, swizzled global source -> linear LDS ----------
template <int R>
__device__ __forceinline__ void stage_bf16(const u16* __restrict__ src, int ld,
                                           char* ldsT, int tid) {
    int w = tid >> 6, l = tid & 63;
    int cc = l & 7, rsub = l >> 3;
#pragma unroll
    for (int i = w; i < R / 8; i += 4) {
        int row = i * 8 + rsub;
        const u16* g = src + (long)row * ld + ((cc ^ (row & 7)) << 3);
        gl_lds16(g, ldsT + i * 1024);      // uniform per wave-issue
    }
}

// swizzled read: global chunk kc of row -> LDS chunk kc ^ (row&7)
__device__ __forceinline__ bf16x8 ld_frag(const char* base, int row, int kbyte) {
    return *(const bf16x8*)(base + row * 128 + (kbyte ^ ((row & 7) << 4)));
}

// ---------- split-precision bf16 MFMA GEMM: C = alpha*(A @ W^T) + bias ----------
// A,W pre-split (hi,lo) bf16. acc = Ah*Wh + Ah*Wl + Al*Wh (3-pass, ~fp32).
// batching: gz = z+zoff; zb=gz>>3, zh=gz&7; A += z*aZl + zb*aZb + zh*aZh; W += zb*wZb+zh*wZh;
// C += z*cZl + zb*cZb + zh*cZh. OUT_QKV routes cols: [0,512)->Chi/Clo buf0 (q),
// [512,1024)->buf1 (k, +1048576 elems), [1024,1536)->Vhi/Vlo RESHAPED-slab transpose:
// reference view(B,H,-1,dk) is a flat reshape -> slab (b,h) = contiguous 64-seq-row block
// seen as 512x64: Vr[i][j] = Vproj[b, s=h*64+i/8, d=(i%8)*64+j]; we store vt[z][j][i] (ld 512).
template <int BM, int BN, int OM>
__global__ __launch_bounds__(256) void gemm_bs(
    const u16* __restrict__ Ahi, const u16* __restrict__ Alo, int lda,
    long aZl, long aZb, long aZh,
    const u16* __restrict__ Whi, const u16* __restrict__ Wlo, int ldw,
    long wZb, long wZh,
    const float* __restrict__ bias, float alpha, int zoff,
    float* __restrict__ Cf, u16* __restrict__ Chi, u16* __restrict__ Clo,
    int ldc, long cZl, long cZb, long cZh,
    u16* __restrict__ Vhi, u16* __restrict__ Vlo, int colOff, int K) {
    constexpr int FR = BM / 32, FC = BN / 32;
    __shared__ char lds[(BM + BN) * 256];
    constexpr int oAl = BM * 128, oBh = 2 * BM * 128, oBl = 2 * BM * 128 + BN * 128;
    int tid = threadIdx.x;
    int z = blockIdx.z, gz = z + zoff;
    long zb = gz >> 3, zh = gz & 7;
    long aoff = (long)z * aZl + zb * aZb + zh * aZh + (long)blockIdx.x * BM * lda;
    const u16* Ah_p = Ahi + aoff;
    const u16* Al_p = Alo + aoff;
    int bn0 = blockIdx.y * BN;
    long woff = zb * wZb + zh * wZh + (long)bn0 * ldw;
    const u16* Wh_p = Whi + woff;
    const u16* Wl_p = Wlo + woff;

    f32x4 acc[FR][FC];
#pragma unroll
    for (int i = 0; i < FR; ++i)
#pragma unroll
        for (int j = 0; j < FC; ++j) acc[i][j] = (f32x4){0.f, 0.f, 0.f, 0.f};

    int wv = tid >> 6, lane = tid & 63;
    int wr = (wv >> 1) * (BM / 2), wc = (wv & 1) * (BN / 2);
    int lrow = lane & 15, lkb = (lane >> 4) * 16;

    for (int kt = 0; kt < K; kt += 64) {
        __syncthreads();
        stage_bf16<BM>(Ah_p + kt, lda, lds, tid);
        stage_bf16<BM>(Al_p + kt, lda, lds + oAl, tid);
        stage_bf16<BN>(Wh_p + kt, ldw, lds + oBh, tid);
        stage_bf16<BN>(Wl_p + kt, ldw, lds + oBl, tid);
        __syncthreads();   // drains vmcnt (global_load_lds) + protects LDS
#pragma unroll
        for (int kk = 0; kk < 2; ++kk) {
            int kb = kk * 64 + lkb;
            bf16x8 ah[FR], al[FR], bh[FC], bl[FC];
#pragma unroll
            for (int i = 0; i < FR; ++i) {
                int rr = wr + i * 16 + lrow;
                ah[i] = ld_frag(lds, rr, kb);
                al[i] = ld_frag(lds + oAl, rr, kb);
            }
#pragma unroll
            for (int j = 0; j < FC; ++j) {
                int cc = wc + j * 16 + lrow;
                bh[j] = ld_frag(lds + oBh, cc, kb);
                bl[j] = ld_frag(lds + oBl, cc, kb);
            }
#pragma unroll
            for (int i = 0; i < FR; ++i)
#pragma unroll
                for (int j = 0; j < FC; ++j) {
                    acc[i][j] = __builtin_amdgcn_mfma_f32_16x16x32_bf16(ah[i], bh[j], acc[i][j], 0, 0, 0);
                    acc[i][j] = __builtin_amdgcn_mfma_f32_16x16x32_bf16(ah[i], bl[j], acc[i][j], 0, 0, 0);
                    acc[i][j] = __builtin_amdgcn_mfma_f32_16x16x32_bf16(al[i], bh[j], acc[i][j], 0, 0, 0);
                }
        }
    }

    // epilogue: C/D layout col=lane&15, row=(lane>>4)*4+r  [m89]
    long crow0 = (long)blockIdx.x * BM;
    long coffC = (long)z * cZl + zb * cZb + zh * cZh;
#pragma unroll
    for (int i = 0; i < FR; ++i) {
        int rowl = wr + i * 16 + (lane >> 4) * 4;
#pragma unroll
        for (int j = 0; j < FC; ++j) {
            int coll = wc + j * 16 + lrow;
            int gc = colOff + bn0 + coll;
            float bv = bias ? bias[gc] : 0.0f;
#pragma unroll
            for (int r = 0; r < 4; ++r) {
                float v = acc[i][j][r] * alpha + bv;
                long row = crow0 + rowl + r;
                if constexpr (OM == OUT_F32) {
                    Cf[coffC + row * ldc + bn0 + coll] = v;
                } else if constexpr (OM == OUT_SPLIT || OM == OUT_SRELU) {
                    if constexpr (OM == OUT_SRELU) v = fmaxf(v, 0.0f);
                    u16 h, l; split2(v, h, l);
                    long o = coffC + row * ldc + bn0 + coll;
                    Chi[o] = h; Clo[o] = l;
                } else {  // OUT_QKV
                    u16 h, l; split2(v, h, l);
                    int buf = gc >> 9;
                    if (buf < 2) {
                        long o = (long)buf * 1048576 + row * ldc + (gc & 511);
                        Chi[o] = h; Clo[o] = l;
                    } else {  // V: reshaped-slab transpose (see header comment)
                        int c2 = gc - 1024;                  // d in [0,512)
                        int bq = (int)(row >> 9), ss = (int)(row & 511);
                        int hq = ss >> 6;
                        int ii = (ss & 63) * 8 + (c2 >> 6);  // pseudo-position
                        int jj = c2 & 63;                    // dk index
                        long o = ((long)(bq * 8 + hq)) * 32768 + (long)jj * 512 + ii;
                        Vhi[o] = h; Vlo[o] = l;
                    }
                }
            }
        }
    }
}

// ---------- orchestration ----------
extern "C" void kernel_launch(void* const* d_in, const int* in_sizes, int n_in,
                              void* d_out, int out_size, void* d_ws, size_t ws_size,
                              hipStream_t stream) {
    const int*   src_words    = (const int*)d_in[0];
    const float* target_words = (const float*)d_in[1];
    const int*   src_mask     = (const int*)d_in[2];
    const int*   target_mask  = (const int*)d_in[3];
    const float* emb          = (const float*)d_in[4];
    const float* pos_emb      = (const float*)d_in[5];
    const float* enc_ln_g     = (const float*)d_in[6];
    const float* enc_ln_b     = (const float*)d_in[7];
    const float* enc_attn_w   = (const float*)d_in[8];
    const float* enc_attn_b   = (const float*)d_in[9];
    const float* enc_fc1_w    = (const float*)d_in[10];
    const float* enc_fc1_b    = (const float*)d_in[11];
    const float* enc_fc2_w    = (const float*)d_in[12];
    const float* enc_fc2_b    = (const float*)d_in[13];
    const float* dec_ln_g     = (const float*)d_in[14];
    const float* dec_ln_b     = (const float*)d_in[15];
    const float* dec_self_w   = (const float*)d_in[16];
    const float* dec_self_b   = (const float*)d_in[17];
    const float* dec_src_w    = (const float*)d_in[18];
    const float* dec_src_b    = (const float*)d_in[19];
    const float* dec_fc1_w    = (const float*)d_in[20];
    const float* dec_fc1_b    = (const float*)d_in[21];
    const float* dec_fc2_w    = (const float*)d_in[22];
    const float* dec_fc2_b    = (const float*)d_in[23];
    float* out = (float*)d_out;

    const size_t Mi = 1u << 20;
    char* W = (char*)d_ws;
    // nchunk: attention z-batch split so scores region fits proven ws budget
    int nchunk;
    if (ws_size >= 80 * Mi) nchunk = 1;
    else if (ws_size >= 64 * Mi) nchunk = 2;
    else return;

    float* x_enc = (float*)(W + 0);           // decoder: t3 aliases this
    float* t1    = (float*)(W + 4 * Mi);
    float* t2    = (float*)(W + 8 * Mi);
    float* ybuf  = (float*)(W + 12 * Mi);
    u16* xs_h  = (u16*)(W + 16 * Mi); u16* xs_l  = (u16*)(W + 18 * Mi);
    u16* t2s_h = (u16*)(W + 20 * Mi); u16* t2s_l = (u16*)(W + 22 * Mi);  // also ys
    u16* t3s_h = (u16*)(W + 24 * Mi); u16* t3s_l = (u16*)(W + 26 * Mi);
    u16* qk_h  = (u16*)(W + 28 * Mi);  // q at +0, k at +1048576 elems
    u16* qk_l  = (u16*)(W + 32 * Mi);
    u16* vt_h  = (u16*)(W + 36 * Mi); u16* vt_l  = (u16*)(W + 38 * Mi);
    u16* cx_h  = (u16*)(W + 40 * Mi); u16* cx_l  = (u16*)(W + 42 * Mi);
    u16* w_h   = (u16*)(W + 44 * Mi); u16* w_l   = (u16*)(W + 46 * Mi);
    char* region = W + 48 * Mi;               // scores/P per chunk; FFN: hs
    u16* hs_h = (u16*)region;
    u16* hs_l = (u16*)(region + 8 * Mi);
    float* t3 = x_enc;
    u16 *ys_h = t2s_h, *ys_l = t2s_l;

    auto conv = [&](const float* src, int n) {
        int n8 = n / 8;
        split_conv<<<dim3((n8 + 255) / 256), 256, 0, stream>>>(src, w_h, w_l, n8);
    };
    auto attention = [&](int mode, const int* mask) {
        int ns = 32 / nchunk;
        for (int c = 0; c < nchunk; ++c) {
            int zoff = c * ns;
            // scores = Qr Kr^T / 8 ; Qr/Kr = contiguous reshaped slabs (ld 64, slab 32768)
            gemm_bs<64, 64, OUT_F32><<<dim3(8, 8, ns), 256, 0, stream>>>(
                qk_h, qk_l, 64, 0, 262144, 32768,
                qk_h + 1048576, qk_l + 1048576, 64, 262144, 32768,
                nullptr, 0.125f, zoff,
                (float*)region, nullptr, nullptr, 512, 262144, 0, 0,
                nullptr, nullptr, 0, 64);
            if (mode == 0) softmax_rows<0><<<dim3(ns * 128), 256, 0, stream>>>((float*)region, nullptr, zoff);
            if (mode == 1) softmax_rows<1><<<dim3(ns * 128), 256, 0, stream>>>((float*)region, mask, zoff);
            if (mode == 2) softmax_rows<2><<<dim3(ns * 128), 256, 0, stream>>>((float*)region, mask, zoff);
            // ctx = P Vr  (P split interleaved in region rows; vt = reshaped-slab transpose)
            gemm_bs<32, 64, OUT_SPLIT><<<dim3(16, 1, ns), 256, 0, stream>>>(
                (u16*)region, (u16*)region + 512, 1024, 524288, 0, 0,
                vt_h, vt_l, 512, 262144, 32768,
                nullptr, 1.0f, zoff,
                nullptr, cx_h, cx_l, 512, 0, 262144, 64,
                nullptr, nullptr, 0, 512);
        }
    };

    embed_k<<<dim3(512), 256, 0, stream>>>(src_words, emb, pos_emb, x_enc, xs_h, xs_l);

    // ===== encoder =====
    for (int i = 0; i < 4; ++i) {
        const float* Wl = enc_attn_w + (size_t)i * 4 * DDW;
        const float* bl = enc_attn_b + (size_t)i * 4 * ND;
        const float* g  = enc_ln_g + (size_t)i * ND;
        const float* be = enc_ln_b + (size_t)i * ND;
        conv(Wl, 3 * DDW);
        gemm_bs<64, 64, OUT_QKV><<<dim3(32, 24, 1), 256, 0, stream>>>(
            xs_h, xs_l, 512, 0, 0, 0, w_h, w_l, 512, 0, 0,
            bl, 1.0f, 0, nullptr, qk_h, qk_l, 512, 0, 0, 0,
            vt_h, vt_l, 0, 512);
        attention(1, src_mask);
        conv(Wl + 3 * DDW, DDW);
        gemm_bs<64, 32, OUT_F32><<<dim3(32, 16, 1), 256, 0, stream>>>(
            cx_h, cx_l, 512, 0, 0, 0, w_h, w_l, 512, 0, 0,
            bl + 1536, 1.0f, 0, t1, nullptr, nullptr, 512, 0, 0, 0,
            nullptr, nullptr, 0, 512);
        add_ln_k<<<dim3(512), 256, 0, stream>>>(t1, x_enc, g, be, t2, t2s_h, t2s_l);
        conv(enc_fc1_w + (size_t)i * NMID * ND, NMID * ND);
        gemm_bs<64, 64, OUT_SRELU><<<dim3(32, 32, 1), 256, 0, stream>>>(
            t2s_h, t2s_l, 512, 0, 0, 0, w_h, w_l, 512, 0, 0,
            enc_fc1_b + (size_t)i * NMID, 1.0f, 0,
            nullptr, hs_h, hs_l, 2048, 0, 0, 0, nullptr, nullptr, 0, 512);
        conv(enc_fc2_w + (size_t)i * ND * NMID, ND * NMID);
        gemm_bs<64, 32, OUT_F32><<<dim3(32, 16, 1), 256, 0, stream>>>(
            hs_h, hs_l, 2048, 0, 0, 0, w_h, w_l, 2048, 0, 0,
            enc_fc2_b + (size_t)i * ND, 1.0f, 0,
            t1, nullptr, nullptr, 512, 0, 0, 0, nullptr, nullptr, 0, 2048);
        add_ln_k<<<dim3(512), 256, 0, stream>>>(t1, t2, g, be, x_enc, xs_h, xs_l);
    }

    // ===== decoder =====
    split_conv<<<dim3(512), 256, 0, stream>>>(target_words, ys_h, ys_l, 131072);
    const float* yres = target_words;
    for (int i = 0; i < 4; ++i) {
        const float* Ws = dec_self_w + (size_t)i * 4 * DDW;
        const float* bs = dec_self_b + (size_t)i * 4 * ND;
        const float* Wx = dec_src_w + (size_t)i * 4 * DDW;
        const float* bx = dec_src_b + (size_t)i * 4 * ND;
        const float* g  = dec_ln_g + (size_t)i * ND;
        const float* be = dec_ln_b + (size_t)i * ND;
        // --- self attention ---
        conv(Ws, 3 * DDW);
        gemm_bs<64, 64, OUT_QKV><<<dim3(32, 24, 1), 256, 0, stream>>>(
            ys_h, ys_l, 512, 0, 0, 0, w_h, w_l, 512, 0, 0,
            bs, 1.0f, 0, nullptr, qk_h, qk_l, 512, 0, 0, 0,
            vt_h, vt_l, 0, 512);
        attention(2, target_mask);
        conv(Ws + 3 * DDW, DDW);
        gemm_bs<64, 32, OUT_F32><<<dim3(32, 16, 1), 256, 0, stream>>>(
            cx_h, cx_l, 512, 0, 0, 0, w_h, w_l, 512, 0, 0,
            bs + 1536, 1.0f, 0, t1, nullptr, nullptr, 512, 0, 0, 0,
            nullptr, nullptr, 0, 512);
        add_ln_k<<<dim3(512), 256, 0, stream>>>(t1, yres, g, be, t2, t2s_h, t2s_l);
        // --- cross attention: Q from t2; K,V from encoder output (xs) ---
        conv(Wx, 3 * DDW);
        gemm_bs<64, 32, OUT_QKV><<<dim3(32, 16, 1), 256, 0, stream>>>(
            t2s_h, t2s_l, 512, 0, 0, 0, w_h, w_l, 512, 0, 0,
            bx, 1.0f, 0, nullptr, qk_h, qk_l, 512, 0, 0, 0,
            vt_h, vt_l, 0, 512);
        gemm_bs<64, 64, OUT_QKV><<<dim3(32, 16, 1), 256, 0, stream>>>(
            xs_h, xs_l, 512, 0, 0, 0, w_h + 512 * 512, w_l + 512 * 512, 512, 0, 0,
            bx, 1.0f, 0, nullptr, qk_h, qk_l, 512, 0, 0, 0,
            vt_h, vt_l, 512, 512);
        attention(0, nullptr);
        conv(Wx + 3 * DDW, DDW);
        gemm_bs<64, 32, OUT_F32><<<dim3(32, 16, 1), 256, 0, stream>>>(
            cx_h, cx_l, 512, 0, 0, 0, w_h, w_l, 512, 0, 0,
            bx + 1536, 1.0f, 0, t1, nullptr, nullptr, 512, 0, 0, 0,
            nullptr, nullptr, 0, 512);
        add_ln_k<<<dim3(512), 256, 0, stream>>>(t1, t2, g, be, t3, t3s_h, t3s_l);
        // --- FFN ---
        conv(dec_fc1_w + (size_t)i * NMID * ND, NMID * ND);
        gemm_bs<64, 64, OUT_SRELU><<<dim3(32, 32, 1), 256, 0, stream>>>(
            t3s_h, t3s_l, 512, 0, 0, 0, w_h, w_l, 512, 0, 0,
            dec_fc1_b + (size_t)i * NMID, 1.0f, 0,
            nullptr, hs_h, hs_l, 2048, 0, 0, 0, nullptr, nullptr, 0, 512);
        conv(dec_fc2_w + (size_t)i * ND * NMID, ND * NMID);
        gemm_bs<64, 32, OUT_F32><<<dim3(32, 16, 1), 256, 0, stream>>>(
            hs_h, hs_l, 2048, 0, 0, 0, w_h, w_l, 2048, 0, 0,
            dec_fc2_b + (size_t)i * ND, 1.0f, 0,
            t1, nullptr, nullptr, 512, 0, 0, 0, nullptr, nullptr, 0, 2048);
        add_ln_k<<<dim3(512), 256, 0, stream>>>(t1, t3, g, be, (i == 3) ? out : ybuf, ys_h, ys_l);
        yres = ybuf;
    }
}